// Round 8
// baseline (75.976 us; speedup 1.0000x reference)
//
#include <hip/hip_runtime.h>

#define IN_F    512
#define NC      4096    // OUT_F*KD
#define OUT_COLS 640
#define AS_PITCH 136    // ushort pitch for A/B K-tiles (128+8)
#define MO_PITCH 36     // float pitch for mo
#define BK      128

typedef __attribute__((ext_vector_type(8))) short  bf16x8;
typedef __attribute__((ext_vector_type(4))) float  f32x4;

static __device__ __forceinline__ unsigned short f2bfu(float f) {
    return (unsigned short)(__float_as_uint(f) >> 16);   // bf16 truncation
}
static __device__ __forceinline__ unsigned int pack2(float lo, float hi) {
    return (__float_as_uint(lo) >> 16) | (__float_as_uint(hi) & 0xFFFF0000u);
}

// One block = (o, jhalf): computes m-strip [128 rows][32 cols n=o*32..] via MFMA
// entirely in LDS, then o_b[jhalf*64..+63][o] from the same LDS. Also copies its
// 1/256 slice of x -> out. No workspace, single launch.
__global__ __launch_bounds__(1024, 4) void fused_kernel(
    const float* __restrict__ x,            // fp32 [128][512]
    const float* __restrict__ T,            // fp32 [512][4096]
    float* __restrict__ out)                // fp32 [128][640]
{
    __shared__ __align__(16) char smem[51968];
    unsigned short* as = (unsigned short*)smem;             // [128][136] bf16 A-tile
    unsigned short* bs = (unsigned short*)(smem + 34816);   // [32][136]  bf16 B^T-tile
    float* mo   = (float*)smem;                             // [128][36]  overlay (phase 2)
    float* psum = (float*)(smem + 43520);                   // [2][32][33]

    const int tid   = threadIdx.x;
    const int lane  = tid & 63;
    const int w     = tid >> 6;             // wave 0..15
    const int col   = lane & 15;
    const int q     = lane >> 4;            // quad
    const int o     = blockIdx.x >> 1;
    const int jhalf = blockIdx.x & 1;
    const int mt    = w >> 1;               // m-tile 0..7
    const int nt    = w & 1;                // n-tile 0..1

    // fused x -> out[:, :512] copy (bit-exact), 64 float4 per block
    if (tid < 64) {
        int idx = blockIdx.x * 64 + tid;
        int b = idx >> 7, c4 = idx & 127;
        float4 v = ((const float4*)x)[idx];
        *(float4*)(out + b * OUT_COLS + c4 * 4) = v;
    }

    // ---------- Phase 1: GEMM, M=128 N=32 K=512, BK=128 ----------
    f32x4 acc = {0.f, 0.f, 0.f, 0.f};
    for (int k0 = 0; k0 < IN_F; k0 += BK) {
        __syncthreads();
        // stage A: x[0..127][k0..k0+127] fp32 -> bf16, coalesced float4 reads
        #pragma unroll
        for (int p = 0; p < 4; ++p) {
            int u   = tid + p * 1024;       // 0..4095 float4 units
            int row = u >> 5, c4 = u & 31;
            float4 v = *(const float4*)(x + row * IN_F + k0 + c4 * 4);
            uint2 pv;
            pv.x = pack2(v.x, v.y); pv.y = pack2(v.z, v.w);
            *(uint2*)(as + row * AS_PITCH + c4 * 4) = pv;   // 8B-aligned b64
        }
        // stage B^T: T[k0+kk][o*32+c] -> bs[c][kk]
        {
            int kk = tid >> 3, cq = tid & 7;
            float4 v = *(const float4*)(T + (size_t)(k0 + kk) * NC + o * 32 + cq * 4);
            int nb = cq * 4;
            bs[(nb + 0) * AS_PITCH + kk] = f2bfu(v.x);
            bs[(nb + 1) * AS_PITCH + kk] = f2bfu(v.y);
            bs[(nb + 2) * AS_PITCH + kk] = f2bfu(v.z);
            bs[(nb + 3) * AS_PITCH + kk] = f2bfu(v.w);
        }
        __syncthreads();
        #pragma unroll
        for (int kt = 0; kt < 4; ++kt) {
            const int krel = kt * 32 + q * 8;
            bf16x8 af  = *(const bf16x8*)(as + (mt * 16 + col) * AS_PITCH + krel);
            bf16x8 bfr = *(const bf16x8*)(bs + (nt * 16 + col) * AS_PITCH + krel);
            acc = __builtin_amdgcn_mfma_f32_16x16x32_bf16(af, bfr, acc, 0, 0, 0);
        }
    }
    __syncthreads();                        // all as/bs reads done -> overlay safe
    // epilogue: acc -> mo. C/D: row = q*4+r, col = lane&15 (verified mapping)
    {
        float* dst = mo + (size_t)(mt * 16 + q * 4) * MO_PITCH + nt * 16 + col;
        dst[0 * MO_PITCH] = acc[0]; dst[1 * MO_PITCH] = acc[1];
        dst[2 * MO_PITCH] = acc[2]; dst[3 * MO_PITCH] = acc[3];
    }
    __syncthreads();

    // ---------- Phase 2: o_b[j][o] = sum_i exp(-L1(m_i, m_j)) - 1 ----------
    // thread = (jj5 = tid&31, isl = tid>>5 in 0..31); handles j0=jhalf*64+jj5,
    // j1 = j0+32, i in [isl*4, isl*4+4). 2 j per mi-read halves LDS traffic.
    const int jj5 = tid & 31;
    const int isl = tid >> 5;
    const int j0  = jhalf * 64 + jj5;

    float mj0[32], mj1[32];
    #pragma unroll
    for (int k4 = 0; k4 < 8; ++k4) {
        float4 a = *(const float4*)(mo + (size_t)j0 * MO_PITCH + k4 * 4);
        float4 b = *(const float4*)(mo + (size_t)(j0 + 32) * MO_PITCH + k4 * 4);
        mj0[k4*4+0] = a.x; mj0[k4*4+1] = a.y; mj0[k4*4+2] = a.z; mj0[k4*4+3] = a.w;
        mj1[k4*4+0] = b.x; mj1[k4*4+1] = b.y; mj1[k4*4+2] = b.z; mj1[k4*4+3] = b.w;
    }

    float s0 = 0.f, s1 = 0.f;
    #pragma unroll
    for (int ii = 0; ii < 4; ++ii) {
        const int i = isl * 4 + ii;
        float n0 = 0.f, n1 = 0.f;
        #pragma unroll
        for (int k4 = 0; k4 < 8; ++k4) {
            float4 v = *(const float4*)(mo + (size_t)i * MO_PITCH + k4 * 4); // 2-addr/wave
            n0 += fabsf(mj0[k4*4+0] - v.x) + fabsf(mj0[k4*4+1] - v.y)
                + fabsf(mj0[k4*4+2] - v.z) + fabsf(mj0[k4*4+3] - v.w);
            n1 += fabsf(mj1[k4*4+0] - v.x) + fabsf(mj1[k4*4+1] - v.y)
                + fabsf(mj1[k4*4+2] - v.z) + fabsf(mj1[k4*4+3] - v.w);
        }
        s0 += __expf(-n0);                  // i==j term = exp(0)=1, removed by -1
        s1 += __expf(-n1);
    }
    psum[jj5 * 33 + isl]        = s0;       // pitch 33 -> conflict-free
    psum[1056 + jj5 * 33 + isl] = s1;
    __syncthreads();
    if (tid < 64) {
        int jsel = tid >> 5, jj = tid & 31;
        float tot = 0.f;
        #pragma unroll
        for (int u = 0; u < 32; ++u) tot += psum[jsel * 1056 + jj * 33 + u];
        out[(jhalf * 64 + jsel * 32 + jj) * OUT_COLS + IN_F + o] = tot - 1.0f;
    }
}

extern "C" void kernel_launch(void* const* d_in, const int* in_sizes, int n_in,
                              void* d_out, int out_size, void* d_ws, size_t ws_size,
                              hipStream_t stream) {
    const float* x = (const float*)d_in[0];
    const float* T = (const float*)d_in[1];
    float* out = (float*)d_out;
    (void)d_ws; (void)ws_size;

    fused_kernel<<<256, 1024, 0, stream>>>(x, T, out);
}